// Round 10
// baseline (49.964 us; speedup 1.0000x reference)
//
#include <hip/hip_runtime.h>

#define NCAM   6
#define FHW    72        // FH*FW
#define EMBED  128
#define NG     432       // gaussians per scale
#define THRESH 0.01f
#define AMIN   (1.0f/255.0f)
#define NTILES 891
#define TC     432       // per-tile list capacity
// tiles are 4 rows x 16 cols:
// s0: 7x2=14 [0,14) H=25 | s1: 13x4=52 [14,66) H=50
// s2: 25x7=175 [66,241) H=100 | s3: 50x13=650 [241,891) H=200

struct Args {
    const float* feat[4];
    const float* mean[4];
    const float* unc[4];
    const float* opac[4];
};

__device__ __forceinline__ void tile_decode(int g, int& s, int& H, int& band, int& chunk)
{
    int tb;
    if (g < 14)       { s = 0; H = 25;  tb = g;       chunk = tb & 1;  band = tb >> 1; }
    else if (g < 66)  { s = 1; H = 50;  tb = g - 14;  chunk = tb & 3;  band = tb >> 2; }
    else if (g < 241) { s = 2; H = 100; tb = g - 66;  band = tb / 7;   chunk = tb - band * 7; }
    else              { s = 3; H = 200; tb = g - 241; band = tb / 13;  chunk = tb - band * 13; }
}

// K1: [0,891) tile cull + 4-wave-split w-scan; [891,915) ft transpose; 915 count
__global__ __launch_bounds__(256) void prep(Args a, float* __restrict__ ft,
                                            int* __restrict__ tlen,
                                            unsigned* __restrict__ tofs,
                                            float* __restrict__ w_ws,
                                            float* __restrict__ out)
{
    int b = blockIdx.x, t = threadIdx.x;
    if (b < NTILES) {
        __shared__ float4 e0[TC];     // pr, pc, qa, qb
        __shared__ float4 e1[TC];     // qc, ok, -, -
        __shared__ int s_cnt[8];
        __shared__ float s_tq[4][64]; // per-quarter transmittance products
        int g = b;
        int s, H, band, chunk;
        tile_decode(g, s, H, band, chunk);
        int lane = t & 63, wv = t >> 6;
        float sh = H * 0.01f;
        float r0f = (float)(band * 4), r1f = (float)min(band * 4 + 3, H - 1);
        float c0f = (float)(chunk * 16), c1f = (float)min(chunk * 16 + 15, H - 1);
        const float* mean = a.mean[s];
        const float* unc  = a.unc[s];
        const float* opac = a.opac[s];

        bool v_act[2]; int v_rnk[2];
        float v_pr[2], v_pc[2], v_qa[2], v_qb[2], v_qc[2], v_ok[2];
        #pragma unroll
        for (int pp = 0; pp < 2; pp++) {
            int j = pp * 256 + t;
            bool act = false;
            float pr = 0.f, pc = 0.f, qa = 0.f, qb = 0.f, qc = 0.f, ok = 0.f;
            if (j < NG) {
                float m0 = mean[j*3+0], m1 = mean[j*3+1];
                float u00 = fmaxf(unc[j*9+0], 1.f);
                float u01 = fmaxf(unc[j*9+1], 1.f);
                float u11 = fmaxf(unc[j*9+4], 1.f);
                float op = opac[j];
                pr = -sh*m1 + H*0.5f;
                pc = -sh*m0 + H*0.5f;
                float va = sh*sh*u11 + 0.3f;
                float vb = sh*sh*u01;
                float vc = sh*sh*u00 + 0.3f;
                float det = va*vc - vb*vb;
                if (op > THRESH && det > 0.f) {
                    float inv = 1.f/det;
                    qa = 0.5f*vc*inv;                      // dr^2 coeff
                    qc = 0.5f*va*inv;                      // dc^2 coeff
                    qb = vb*inv;                           // dr*dc coeff
                    ok = op;
                    float thr = __logf(255.f*op);          // alpha >= 1/255 level set
                    float Rr = sqrtf(2.f*va*thr) + 1e-2f;  // max |dr| on level set
                    float Rc = sqrtf(2.f*vc*thr) + 1e-2f;  // max |dc| on level set
                    act = (pr >= r0f-Rr) && (pr <= r1f+Rr) &&
                          (pc >= c0f-Rc) && (pc <= c1f+Rc);
                }
            }
            unsigned long long m = __ballot(act);
            v_act[pp] = act;
            v_rnk[pp] = __popcll(m & ((1ull << lane) - 1ull));
            v_pr[pp]=pr; v_pc[pp]=pc; v_qa[pp]=qa; v_qb[pp]=qb; v_qc[pp]=qc; v_ok[pp]=ok;
            if (lane == 0) s_cnt[pp*4 + wv] = __popcll(m);
        }
        __syncthreads();
        int c8[8];
        #pragma unroll
        for (int i = 0; i < 8; i++) c8[i] = s_cnt[i];
        int len = 0;
        #pragma unroll
        for (int i = 0; i < 8; i++) len += c8[i];
        #pragma unroll
        for (int pp = 0; pp < 2; pp++) {
            int slot = pp*4 + wv;
            int pre = 0;
            #pragma unroll
            for (int i = 0; i < 8; i++) pre += (i < slot) ? c8[i] : 0;
            if (v_act[pp]) {
                int idx = pre + v_rnk[pp];
                e0[idx] = make_float4(v_pr[pp], v_pc[pp], v_qa[pp], v_qb[pp]);
                e1[idx] = make_float4(v_qc[pp], v_ok[pp], 0.f, 0.f);
                int j = pp * 256 + t;
                tofs[g*TC + idx] = (unsigned)((s*NG + j) * EMBED);
            }
        }
        if (t == 0) tlen[g] = len;
        __syncthreads();

        // ---- 4-wave-split w-scan: wave wv scans quarter [k0,k1) with local T ----
        if (len > 0) {
            int qlen = (len + 3) >> 2;
            int k0 = wv * qlen, k1 = min(k0 + qlen, len);
            int row = band*4 + (lane >> 4), col = chunk*16 + (lane & 15);
            float frow = (float)row, fcol = (float)col;
            float T = 1.f;
            float* wrow = w_ws + (size_t)g * (TC*64) + lane;
            for (int k = k0; k < k1; k++) {
                float4 A = e0[k];
                float4 B = e1[k];
                float dr = A.x - frow, dc = A.y - fcol;
                float pw = A.w*dr*dc - A.z*dr*dr - B.x*dc*dc;
                float aL = 0.f;
                if (pw <= 0.f) {
                    aL = fminf(B.y * __expf(pw), 0.99f);
                    aL = (aL >= AMIN) ? aL : 0.f;
                }
                wrow[k*64] = aL * T;       // provisional: local-quarter T_excl
                T *= (1.f - aL);
            }
            s_tq[wv][lane] = T;
            __syncthreads();
            // prefix over earlier quarters, then fix-up pass
            float pref = 1.f;
            #pragma unroll
            for (int q = 0; q < 3; q++)
                if (q < wv) pref *= s_tq[q][lane];
            if (wv > 0) {
                for (int k = k0; k < k1; k++)
                    wrow[k*64] *= pref;
            }
        }
    } else if (b < NTILES + 24) {
        // LDS-staged feature transpose: ft[s*NG+n][d] = feat[cam][d][hw]
        __shared__ float l[EMBED * 73];
        int sc = b - NTILES;
        int s = sc / NCAM, cam = sc - s * NCAM;
        const float* src = a.feat[s] + cam * (EMBED * FHW);
        for (int i = t; i < EMBED * FHW; i += 256) {
            int d = i / FHW, hw = i - d * FHW;
            l[d * 73 + hw] = src[i];
        }
        __syncthreads();
        float* dst = ft + (s * NG + cam * FHW) * EMBED;
        for (int e = t; e < EMBED * FHW; e += 256) {
            int hw = e >> 7, d = e & 127;
            dst[hw * EMBED + d] = l[d * 73 + hw];
        }
    } else {
        __shared__ float red[256];
        float c = 0.f;
        for (int s = 0; s < 4; s++)
            for (int i = t; i < NG; i += 256)
                c += (a.opac[s][i] > THRESH) ? 1.f : 0.f;
        red[t] = c;
        __syncthreads();
        for (int st = 128; st > 0; st >>= 1) {
            if (t < st) red[t] += red[t + st];
            __syncthreads();
        }
        if (t == 0) out[6800000] = red[0];
    }
}

// K2: outer-product weighted sum. block = tile; wave = 8 cg x 8 pg;
// wave wv: chh = wv&1 (64-ch half), pxh = wv>>1 (32-px half).
// thread tile 8ch x 4px: per k = 3 distinct-address b128 reads (128B/op) + 32 FMA.
#define FPAD 132
#define WPAD 68
__global__ __launch_bounds__(256) void render(const float* __restrict__ ft,
                                              const int* __restrict__ tlen,
                                              const unsigned* __restrict__ tofs,
                                              const float* __restrict__ w_ws,
                                              float* __restrict__ out)
{
    __shared__ float s_f[2][32][FPAD];
    __shared__ float s_w[2][32][WPAD];
    __shared__ unsigned s_to[TC];

    int g = blockIdx.x, t = threadIdx.x;
    int s, H, band, chunk;
    tile_decode(g, s, H, band, chunk);
    int P = H * H;
    float* o = out + ((s == 0) ? 0 : (s == 1) ? 80000 : (s == 2) ? 400000 : 1680000);
    int lane = t & 63, wv = t >> 6;
    int cg = lane >> 3, pg = lane & 7;
    int chh = wv & 1, pxh = wv >> 1;
    int len = tlen[g];
    const float* wg = w_ws + (size_t)g * (TC * 64);

    for (int idx = t; idx < len; idx += 256) s_to[idx] = tofs[g*TC + idx];

    // staging mapping: list-row kr = t>>3, slice fs = t&7
    int kr = t >> 3, fs = t & 7;
    float4 rf[4], rw[2];

    #define ISSUE(C0) do {                                                      \
        int k_ = (C0) + kr;                                                     \
        if (k_ < len) {                                                         \
            const float* fp_ = ft + s_to[k_] + fs * 16;                         \
            _Pragma("unroll")                                                   \
            for (int i_ = 0; i_ < 4; i_++)                                      \
                rf[i_] = *reinterpret_cast<const float4*>(fp_ + i_ * 4);        \
            const float* wp_ = wg + k_ * 64 + fs * 8;                           \
            _Pragma("unroll")                                                   \
            for (int i_ = 0; i_ < 2; i_++)                                      \
                rw[i_] = *reinterpret_cast<const float4*>(wp_ + i_ * 4);        \
        } } while (0)

    #define WRITE(C0, BUF) do {                                                 \
        if ((C0) + kr < len) {                                                  \
            _Pragma("unroll")                                                   \
            for (int i_ = 0; i_ < 4; i_++)                                      \
                *reinterpret_cast<float4*>(&s_f[BUF][kr][fs*16 + i_*4]) = rf[i_];\
            _Pragma("unroll")                                                   \
            for (int i_ = 0; i_ < 2; i_++)                                      \
                *reinterpret_cast<float4*>(&s_w[BUF][kr][fs*8 + i_*4]) = rw[i_];\
        } } while (0)

    float4 acc4[8];
    #pragma unroll
    for (int i = 0; i < 8; i++) acc4[i] = make_float4(0.f, 0.f, 0.f, 0.f);

    if (len > 0) {
        __syncthreads();                  // s_to ready
        ISSUE(0);
        WRITE(0, 0);
        __syncthreads();
        int buf = 0;
        for (int c0 = 0; c0 < len; c0 += 32) {
            bool more = (c0 + 32) < len;
            if (more) ISSUE(c0 + 32);     // global->reg, hidden under FMA
            int kmax = min(32, len - c0);
            #pragma unroll 2
            for (int k = 0; k < kmax; k++) {
                float4 w4 = *reinterpret_cast<const float4*>(&s_w[buf][k][pxh*32 + pg*4]);
                float4 fa = *reinterpret_cast<const float4*>(&s_f[buf][k][chh*64 + cg*8]);
                float4 fb = *reinterpret_cast<const float4*>(&s_f[buf][k][chh*64 + cg*8 + 4]);
                acc4[0].x += fa.x*w4.x; acc4[0].y += fa.x*w4.y; acc4[0].z += fa.x*w4.z; acc4[0].w += fa.x*w4.w;
                acc4[1].x += fa.y*w4.x; acc4[1].y += fa.y*w4.y; acc4[1].z += fa.y*w4.z; acc4[1].w += fa.y*w4.w;
                acc4[2].x += fa.z*w4.x; acc4[2].y += fa.z*w4.y; acc4[2].z += fa.z*w4.z; acc4[2].w += fa.z*w4.w;
                acc4[3].x += fa.w*w4.x; acc4[3].y += fa.w*w4.y; acc4[3].z += fa.w*w4.z; acc4[3].w += fa.w*w4.w;
                acc4[4].x += fb.x*w4.x; acc4[4].y += fb.x*w4.y; acc4[4].z += fb.x*w4.z; acc4[4].w += fb.x*w4.w;
                acc4[5].x += fb.y*w4.x; acc4[5].y += fb.y*w4.y; acc4[5].z += fb.y*w4.z; acc4[5].w += fb.y*w4.w;
                acc4[6].x += fb.z*w4.x; acc4[6].y += fb.z*w4.y; acc4[6].z += fb.z*w4.z; acc4[6].w += fb.z*w4.w;
                acc4[7].x += fb.w*w4.x; acc4[7].y += fb.w*w4.y; acc4[7].z += fb.w*w4.z; acc4[7].w += fb.w*w4.w;
            }
            if (more) WRITE(c0 + 32, buf ^ 1);   // other buffer: no race with FMA(buf)
            __syncthreads();
            buf ^= 1;
        }
    }
    #undef ISSUE
    #undef WRITE

    // stores: thread tile = 8 ch x 4 px, bounds-checked
    int px0 = pxh * 32 + pg * 4;
    int ch0 = chh * 64 + cg * 8;
    #pragma unroll
    for (int j = 0; j < 4; j++) {
        int px = px0 + j;
        int row = band*4 + (px >> 4), col = chunk*16 + (px & 15);
        if (row < H && col < H) {
            int pp = row * H + col;
            float* ob = o + pp;
            #pragma unroll
            for (int i = 0; i < 8; i++) {
                float v = (j == 0) ? acc4[i].x : (j == 1) ? acc4[i].y
                        : (j == 2) ? acc4[i].z : acc4[i].w;
                ob[(ch0 + i) * P] = v;
            }
        }
    }
}

extern "C" void kernel_launch(void* const* d_in, const int* in_sizes, int n_in,
                              void* d_out, int out_size, void* d_ws, size_t ws_size,
                              hipStream_t stream)
{
    Args a;
    for (int s = 0; s < 4; s++) {
        a.feat[s] = (const float*)d_in[4 * s + 0];
        a.mean[s] = (const float*)d_in[4 * s + 1];
        a.unc[s]  = (const float*)d_in[4 * s + 2];
        a.opac[s] = (const float*)d_in[4 * s + 3];
    }
    float* ws = (float*)d_ws;
    float*    ft    = ws;                          // 221,184 floats
    int*      tlen  = (int*)(ws + 221184);         // 891
    unsigned* tofs  = (unsigned*)(ws + 222080);    // 891*432
    float*    w_ws  = ws + 700000;                 // 891*432*64 floats (~98.5 MB)

    prep<<<NTILES + 24 + 1, 256, 0, stream>>>(a, ft, tlen, tofs, w_ws, (float*)d_out);
    render<<<NTILES, 256, 0, stream>>>(ft, tlen, tofs, w_ws, (float*)d_out);
}

// Round 11
// 27.070 us; speedup vs baseline: 1.8457x; 1.8457x over previous
//
#include <hip/hip_runtime.h>

#define NCAM   6
#define FHW    72        // FH*FW
#define EMBED  128
#define NG     432       // gaussians per scale
#define THRESH 0.01f
#define AMIN   (1.0f/255.0f)
#define NTILES 891
#define TC     432       // per-tile list capacity
// tiles are 4 rows x 16 cols:
// s0: 7x2=14 [0,14) H=25 | s1: 13x4=52 [14,66) H=50
// s2: 25x7=175 [66,241) H=100 | s3: 50x13=650 [241,891) H=200

struct Args {
    const float* feat[4];
    const float* mean[4];
    const float* unc[4];
    const float* opac[4];
};

__device__ __forceinline__ void tile_decode(int g, int& s, int& H, int& band, int& chunk)
{
    int tb;
    if (g < 14)       { s = 0; H = 25;  tb = g;       chunk = tb & 1;  band = tb >> 1; }
    else if (g < 66)  { s = 1; H = 50;  tb = g - 14;  chunk = tb & 3;  band = tb >> 2; }
    else if (g < 241) { s = 2; H = 100; tb = g - 66;  band = tb / 7;   chunk = tb - band * 7; }
    else              { s = 3; H = 200; tb = g - 241; band = tb / 13;  chunk = tb - band * 13; }
}

// K1: [0,891) tile cull -> param streams; [891,915) ft transpose; 915 count
__global__ __launch_bounds__(256) void prep(Args a, float* __restrict__ ft,
                                            int* __restrict__ tlen,
                                            float4* __restrict__ p4a,
                                            float4* __restrict__ p4b,
                                            float* __restrict__ out)
{
    int b = blockIdx.x, t = threadIdx.x;
    if (b < NTILES) {
        __shared__ int s_cnt[8];
        int g = b;
        int s, H, band, chunk;
        tile_decode(g, s, H, band, chunk);
        int lane = t & 63, wv = t >> 6;
        float sh = H * 0.01f;
        float r0f = (float)(band * 4), r1f = (float)min(band * 4 + 3, H - 1);
        float c0f = (float)(chunk * 16), c1f = (float)min(chunk * 16 + 15, H - 1);
        const float* mean = a.mean[s];
        const float* unc  = a.unc[s];
        const float* opac = a.opac[s];

        bool v_act[2]; int v_rnk[2];
        float v_pr[2], v_pc[2], v_qa[2], v_qb[2], v_qc[2], v_ok[2];
        #pragma unroll
        for (int pp = 0; pp < 2; pp++) {
            int j = pp * 256 + t;
            bool act = false;
            float pr = 0.f, pc = 0.f, qa = 0.f, qb = 0.f, qc = 0.f, ok = 0.f;
            if (j < NG) {
                float m0 = mean[j*3+0], m1 = mean[j*3+1];
                float u00 = fmaxf(unc[j*9+0], 1.f);
                float u01 = fmaxf(unc[j*9+1], 1.f);
                float u11 = fmaxf(unc[j*9+4], 1.f);
                float op = opac[j];
                pr = -sh*m1 + H*0.5f;
                pc = -sh*m0 + H*0.5f;
                float va = sh*sh*u11 + 0.3f;
                float vb = sh*sh*u01;
                float vc = sh*sh*u00 + 0.3f;
                float det = va*vc - vb*vb;
                if (op > THRESH && det > 0.f) {
                    float inv = 1.f/det;
                    qa = 0.5f*vc*inv;                      // dr^2 coeff
                    qc = 0.5f*va*inv;                      // dc^2 coeff
                    qb = vb*inv;                           // dr*dc coeff
                    ok = op;
                    float thr = __logf(255.f*op);          // alpha >= 1/255 level set
                    float Rr = sqrtf(2.f*va*thr) + 1e-2f;  // max |dr| on level set
                    float Rc = sqrtf(2.f*vc*thr) + 1e-2f;  // max |dc| on level set
                    act = (pr >= r0f-Rr) && (pr <= r1f+Rr) &&
                          (pc >= c0f-Rc) && (pc <= c1f+Rc);
                }
            }
            unsigned long long m = __ballot(act);
            v_act[pp] = act;
            v_rnk[pp] = __popcll(m & ((1ull << lane) - 1ull));
            v_pr[pp]=pr; v_pc[pp]=pc; v_qa[pp]=qa; v_qb[pp]=qb; v_qc[pp]=qc; v_ok[pp]=ok;
            if (lane == 0) s_cnt[pp*4 + wv] = __popcll(m);
        }
        __syncthreads();
        int c8[8];
        #pragma unroll
        for (int i = 0; i < 8; i++) c8[i] = s_cnt[i];
        int len = 0;
        #pragma unroll
        for (int i = 0; i < 8; i++) len += c8[i];
        #pragma unroll
        for (int pp = 0; pp < 2; pp++) {
            int slot = pp*4 + wv;
            int pre = 0;
            #pragma unroll
            for (int i = 0; i < 8; i++) pre += (i < slot) ? c8[i] : 0;
            if (v_act[pp]) {
                int idx = g*TC + pre + v_rnk[pp];
                int j = pp * 256 + t;
                unsigned off = (unsigned)((s*NG + j) * EMBED);
                p4a[idx] = make_float4(v_pr[pp], v_pc[pp], v_qa[pp], v_qb[pp]);
                p4b[idx] = make_float4(v_qc[pp], v_ok[pp], __uint_as_float(off), 0.f);
            }
        }
        if (t == 0) tlen[g] = len;
    } else if (b < NTILES + 24) {
        // LDS-staged feature transpose: ft[s*NG+n][d] = feat[cam][d][hw]
        __shared__ float l[EMBED * 73];
        int sc = b - NTILES;
        int s = sc / NCAM, cam = sc - s * NCAM;
        const float* src = a.feat[s] + cam * (EMBED * FHW);
        for (int i = t; i < EMBED * FHW; i += 256) {
            int d = i / FHW, hw = i - d * FHW;
            l[d * 73 + hw] = src[i];
        }
        __syncthreads();
        float* dst = ft + (s * NG + cam * FHW) * EMBED;
        for (int e = t; e < EMBED * FHW; e += 256) {
            int hw = e >> 7, d = e & 127;
            dst[hw * EMBED + d] = l[d * 73 + hw];
        }
    } else {
        __shared__ float red[256];
        float c = 0.f;
        for (int s = 0; s < 4; s++)
            for (int i = t; i < NG; i += 256)
                c += (a.opac[s][i] > THRESH) ? 1.f : 0.f;
        red[t] = c;
        __syncthreads();
        for (int st = 128; st > 0; st >>= 1) {
            if (t < st) red[t] += red[t + st];
            __syncthreads();
        }
        if (t == 0) out[6800000] = red[0];
    }
}

// K2: block = (tile g, ch-quarter chq); 4 waves = 4 k-quarters; lane = pixel.
// Hot loop: uniform param + feature-row loads, register-only alpha/T/acc,
// NO LDS and NO sync. Serial T-chain split x4 with exact prefix fix-up:
// acc_q *= prod_{q'<q} Tend_q'  (2 syncs total, in the epilogue).
__global__ __launch_bounds__(256) void render(const float* __restrict__ ft,
                                              const int* __restrict__ tlen,
                                              const float4* __restrict__ p4a,
                                              const float4* __restrict__ p4b,
                                              float* __restrict__ out)
{
    __shared__ float s_T[4][64];
    __shared__ float s_part[3][64][33];   // +1 pad: conflict-free scalar rows

    int bb = blockIdx.x, t = threadIdx.x;
    int g = bb >> 2, chq = bb & 3;
    int s, H, band, chunk;
    tile_decode(g, s, H, band, chunk);
    int P = H * H;
    float* o = out + ((s == 0) ? 0 : (s == 1) ? 80000 : (s == 2) ? 400000 : 1680000);
    int lane = t & 63;
    int wv = __builtin_amdgcn_readfirstlane(t >> 6);
    int ch0 = chq * 32;
    int len = tlen[g];
    int qlen = (len + 3) >> 2;
    int k0 = wv * qlen, k1 = min(k0 + qlen, len);
    int base = g * TC;
    int row = band*4 + (lane >> 4), col = chunk*16 + (lane & 15);
    float frow = (float)row, fcol = (float)col;

    float acc[32];
    #pragma unroll
    for (int i = 0; i < 32; i++) acc[i] = 0.f;
    float T = 1.f;

    for (int k = k0; k < k1; k++) {
        float4 A = p4a[base + k];
        float4 B = p4b[base + k];
        unsigned off = __builtin_amdgcn_readfirstlane(__float_as_uint(B.z));
        const float* fr = ft + off + ch0;      // uniform row -> broadcast loads
        float dr = A.x - frow, dc = A.y - fcol;
        float pw = A.w*dr*dc - A.z*dr*dr - B.x*dc*dc;
        float aL = 0.f;
        if (pw <= 0.f) {
            aL = fminf(B.y * __expf(pw), 0.99f);
            aL = (aL >= AMIN) ? aL : 0.f;
        }
        float w = aL * T;
        T *= (1.f - aL);
        #pragma unroll
        for (int i = 0; i < 32; i += 4) {
            float4 f = *reinterpret_cast<const float4*>(fr + i);
            acc[i]   += w * f.x; acc[i+1] += w * f.y;
            acc[i+2] += w * f.z; acc[i+3] += w * f.w;
        }
    }

    // ---- epilogue: prefix-T rescale + cross-wave reduction ----
    s_T[wv][lane] = T;
    __syncthreads();
    if (wv > 0) {
        float pref = s_T[0][lane];
        if (wv > 1) pref *= s_T[1][lane];
        if (wv > 2) pref *= s_T[2][lane];
        #pragma unroll
        for (int i = 0; i < 32; i++)
            s_part[wv-1][lane][i] = acc[i] * pref;
    }
    __syncthreads();
    if (wv == 0 && row < H && col < H) {
        int pp = row * H + col;
        #pragma unroll
        for (int i = 0; i < 32; i++) {
            float v = acc[i] + s_part[0][lane][i] + s_part[1][lane][i]
                             + s_part[2][lane][i];
            o[(ch0 + i) * P + pp] = v;
        }
    }
}

extern "C" void kernel_launch(void* const* d_in, const int* in_sizes, int n_in,
                              void* d_out, int out_size, void* d_ws, size_t ws_size,
                              hipStream_t stream)
{
    Args a;
    for (int s = 0; s < 4; s++) {
        a.feat[s] = (const float*)d_in[4 * s + 0];
        a.mean[s] = (const float*)d_in[4 * s + 1];
        a.unc[s]  = (const float*)d_in[4 * s + 2];
        a.opac[s] = (const float*)d_in[4 * s + 3];
    }
    float* ws = (float*)d_ws;
    float*  ft   = ws;                                   // 221,184 floats
    int*    tlen = (int*)(ws + 221184);                  // 891 ints
    float4* p4a  = (float4*)(ws + 222080);               // 891*432 float4
    float4* p4b  = p4a + NTILES * TC;                    // 891*432 float4

    prep<<<NTILES + 24 + 1, 256, 0, stream>>>(a, ft, tlen, p4a, p4b, (float*)d_out);
    render<<<NTILES * 4, 256, 0, stream>>>(ft, tlen, p4a, p4b, (float*)d_out);
}